// Round 1
// baseline (370.662 us; speedup 1.0000x reference)
//
#include <hip/hip_runtime.h>
#include <stdint.h>

// Exact global median-of-|x| (rank 45,088,768 order statistic via 31-bit radix
// select on the fp32 bit pattern), then masked copy out = (|x|<=thr ? 0 : x).
// thr replicates jnp fp32 semantics: t = v_k;  thr = (t*0.1f)/0.1f  (RN).

struct Ctrl {
  unsigned prefix;   // bits of the key determined so far
  unsigned rank;     // remaining rank within the current prefix group
  float    thr;      // final threshold
  unsigned pad;
};

#define HB 2048
#define HT 256

__global__ __launch_bounds__(64) void init_ctrl_k(Ctrl* c0, unsigned k0,
                                                  Ctrl* c1, unsigned k1) {
  if (threadIdx.x == 0 && blockIdx.x == 0) {
    c0->prefix = 0u; c0->rank = k0; c0->thr = 0.0f;
    c1->prefix = 0u; c1->rank = k1; c1->thr = 0.0f;
  }
}

// Histogram of ((u >> shift) & (2^bits - 1)) over elements whose bits above
// (shift+bits) equal ctrl->prefix.  u = float bits with sign cleared.
// bits <= 12 -> LDS-aggregated; else direct global atomics (sparse candidates).
__global__ __launch_bounds__(HT) void hist_stage_k(
    const uint4* __restrict__ x4, long long n4,
    const unsigned* __restrict__ xs, long long n,
    unsigned* __restrict__ hist,
    const Ctrl* __restrict__ ctrl,
    int shift, int bits)
{
  __shared__ unsigned lh[4096];
  const unsigned nb = 1u << bits;
  const bool lds = (bits <= 12);
  if (lds) {
    for (unsigned i = threadIdx.x; i < nb; i += blockDim.x) lh[i] = 0u;
    __syncthreads();
  }
  const unsigned prefix = ctrl->prefix;
  const int top = shift + bits;          // <= 31 always
  const unsigned m = nb - 1u;
  const long long stride = (long long)gridDim.x * blockDim.x;
  long long i = (long long)blockIdx.x * blockDim.x + threadIdx.x;
  for (; i < n4; i += stride) {
    uint4 v = x4[i];
    unsigned a = v.x & 0x7fffffffu;
    unsigned b = v.y & 0x7fffffffu;
    unsigned c = v.z & 0x7fffffffu;
    unsigned d = v.w & 0x7fffffffu;
    if (lds) {
      if ((a >> top) == prefix) atomicAdd(&lh[(a >> shift) & m], 1u);
      if ((b >> top) == prefix) atomicAdd(&lh[(b >> shift) & m], 1u);
      if ((c >> top) == prefix) atomicAdd(&lh[(c >> shift) & m], 1u);
      if ((d >> top) == prefix) atomicAdd(&lh[(d >> shift) & m], 1u);
    } else {
      if ((a >> top) == prefix) atomicAdd(&hist[(a >> shift) & m], 1u);
      if ((b >> top) == prefix) atomicAdd(&hist[(b >> shift) & m], 1u);
      if ((c >> top) == prefix) atomicAdd(&hist[(c >> shift) & m], 1u);
      if ((d >> top) == prefix) atomicAdd(&hist[(d >> shift) & m], 1u);
    }
  }
  long long t = n4 * 4 + (long long)blockIdx.x * blockDim.x + threadIdx.x;
  for (; t < n; t += stride) {
    unsigned u = xs[t] & 0x7fffffffu;
    if ((u >> top) == prefix) {
      if (lds) atomicAdd(&lh[(u >> shift) & m], 1u);
      else     atomicAdd(&hist[(u >> shift) & m], 1u);
    }
  }
  if (lds) {
    __syncthreads();
    for (unsigned j = threadIdx.x; j < nb; j += blockDim.x) {
      unsigned cv = lh[j];
      if (cv) atomicAdd(&hist[j], cv);
    }
  }
}

// Locate rank within a histogram of up to 4096 bins (single block, 1024 thr).
__global__ __launch_bounds__(1024) void scan_stage_k(
    const unsigned* __restrict__ hist, int bits, Ctrl* __restrict__ ctrl)
{
  __shared__ unsigned part[1024];
  const unsigned nb = 1u << bits;
  const unsigned per = (nb + 1023u) >> 10;
  const unsigned t = threadIdx.x;
  const unsigned lo = t * per;
  const unsigned hi = (lo + per < nb) ? (lo + per) : nb;
  const unsigned oldPrefix = ctrl->prefix;
  const unsigned r = ctrl->rank;
  unsigned s = 0;
  for (unsigned j = lo; j < hi; ++j) s += hist[j];
  part[t] = s;
  __syncthreads();
  if (t == 0) {
    unsigned run = 0;
    for (int i = 0; i < 1024; ++i) { unsigned tmp = part[i]; part[i] = run; run += tmp; }
  }
  __syncthreads();
  const unsigned base = part[t];
  if (s > 0 && r >= base && r < base + s) {
    unsigned c = base;
    for (unsigned j = lo; j < hi; ++j) {
      unsigned cnt = hist[j];
      if (r < c + cnt) {
        ctrl->prefix = (oldPrefix << bits) | j;
        ctrl->rank = r - c;
        break;
      }
      c += cnt;
    }
  }
}

// 19-bit scan, phase 1: coalesced per-1024-bin chunk sums (512 blocks).
__global__ __launch_bounds__(256) void scan_big1_k(
    const unsigned* __restrict__ hist, unsigned* __restrict__ chunkSums)
{
  __shared__ unsigned red[256];
  const unsigned base = blockIdx.x * 1024u;
  unsigned s = 0;
  for (unsigned i = threadIdx.x; i < 1024u; i += 256u) s += hist[base + i];
  red[threadIdx.x] = s;
  __syncthreads();
  for (unsigned off = 128; off > 0; off >>= 1) {
    if (threadIdx.x < off) red[threadIdx.x] += red[threadIdx.x + off];
    __syncthreads();
  }
  if (threadIdx.x == 0) chunkSums[blockIdx.x] = red[0];
}

// 19-bit scan, phase 2: pick chunk, then in-LDS scan of its 1024 bins.
__global__ __launch_bounds__(1024) void scan_big2_k(
    const unsigned* __restrict__ hist, const unsigned* __restrict__ chunkSums,
    Ctrl* __restrict__ ctrl)
{
  __shared__ unsigned cs[512];
  __shared__ unsigned sc[1024];
  __shared__ unsigned sel[2];   // [0]=chunk idx, [1]=chunk base count
  const unsigned t = threadIdx.x;
  const unsigned oldPrefix = ctrl->prefix;
  const unsigned r = ctrl->rank;
  if (t < 512) cs[t] = chunkSums[t];
  __syncthreads();
  if (t == 0) {
    unsigned run = 0;
    unsigned ci = 0, cb = 0;
    for (int i = 0; i < 512; ++i) {
      unsigned cnt = cs[i];
      if (r >= run && r < run + cnt) { ci = (unsigned)i; cb = run; }
      run += cnt;
    }
    sel[0] = ci; sel[1] = cb;
  }
  __syncthreads();
  const unsigned ci = sel[0];
  const unsigned cb = sel[1];
  const unsigned val = hist[ci * 1024u + t];
  sc[t] = val;
  __syncthreads();
  for (unsigned off = 1; off < 1024; off <<= 1) {
    unsigned add = (t >= off) ? sc[t - off] : 0u;
    __syncthreads();
    sc[t] += add;
    __syncthreads();
  }
  const unsigned incl = sc[t];
  const unsigned excl = incl - val;
  const unsigned rr = r - cb;
  if (val > 0 && rr >= excl && rr < incl) {
    unsigned j = ci * 1024u + t;            // 19-bit sub-key
    ctrl->prefix = (oldPrefix << 19) | j;   // full 31-bit key
    ctrl->rank = rr - excl;
  }
}

// thr = ( (v0*lw + v1*hw) * 0.1f ) / 0.1f   — bit-exact jnp fp32 replication.
__global__ __launch_bounds__(64) void combine_thr_k(Ctrl* a, const Ctrl* b,
                                                    float lw, float hw) {
  if (threadIdx.x == 0 && blockIdx.x == 0) {
    float v0 = __uint_as_float(a->prefix);
    float v1 = __uint_as_float(b->prefix);
    float tq = __fadd_rn(__fmul_rn(v0, lw), __fmul_rn(v1, hw));
    float num = __fmul_rn(tq, 0.1f);
    a->thr = __fdiv_rn(num, 0.1f);
  }
}

__global__ __launch_bounds__(HT) void mask_k(
    const float4* __restrict__ x4, float4* __restrict__ o4, long long n4,
    const float* __restrict__ xs, float* __restrict__ os, long long n,
    const Ctrl* __restrict__ ctrl)
{
  const float thr = ctrl->thr;
  const long long stride = (long long)gridDim.x * blockDim.x;
  long long i = (long long)blockIdx.x * blockDim.x + threadIdx.x;
  for (; i < n4; i += stride) {
    float4 v = x4[i];
    float4 w;
    w.x = (fabsf(v.x) <= thr) ? 0.0f : v.x;
    w.y = (fabsf(v.y) <= thr) ? 0.0f : v.y;
    w.z = (fabsf(v.z) <= thr) ? 0.0f : v.z;
    w.w = (fabsf(v.w) <= thr) ? 0.0f : v.w;
    o4[i] = w;
  }
  long long t = n4 * 4 + (long long)blockIdx.x * blockDim.x + threadIdx.x;
  for (; t < n; t += stride) {
    float v = xs[t];
    os[t] = (fabsf(v) <= thr) ? 0.0f : v;
  }
}

extern "C" void kernel_launch(void* const* d_in, const int* in_sizes, int n_in,
                              void* d_out, int out_size, void* d_ws, size_t ws_size,
                              hipStream_t stream)
{
  const float* x = (const float*)d_in[0];
  const long long N = (long long)in_sizes[0];
  const long long n4 = N >> 2;
  const uint4* x4 = (const uint4*)x;
  const unsigned* xbits = (const unsigned*)x;

  // Replicate jnp.quantile fp32 index math: idx = 0.5f * f32(N-1).
  float idxf = 0.5f * (float)(N - 1);
  float lowf = floorf(idxf);
  float highf = ceilf(idxf);
  float hw = idxf - lowf;     // high weight
  float lw = 1.0f - hw;       // low weight
  unsigned k0 = (unsigned)lowf;
  unsigned k1 = (unsigned)highf;
  int dual = (hw != 0.0f);    // N here gives hw == 0 -> single rank

  // Workspace layout (byte offsets in arena):
  //   ctrl: ws[0..128)      (always in d_ws if it fits)
  //   chunkSums: [128, 2176)
  //   h1 (4096 bins): [4096, 20480)
  //   path B: h2 (4096): [20480, 36864), h3 (128): [36864, 37376)
  //   path A: h2 (524288): [65536, 2162688)
  const size_t needA = 65536 + (size_t)(1u << 19) * 4;  // 2,162,688
  const size_t needB = 37376;
  char* wsb = (char*)d_ws;
  int pathA;
  char* arena;
  if (ws_size >= needA)      { arena = wsb; pathA = 1; }
  else if (ws_size >= needB) { arena = wsb; pathA = 0; }
  else                       { arena = (char*)d_out; pathA = 1; } // d_out >> needA; fully rewritten at the end
  Ctrl* c0 = (ws_size >= 128) ? (Ctrl*)wsb : (Ctrl*)(arena);
  Ctrl* c1 = c0 + 1;
  unsigned* chunkSums = (unsigned*)(arena + 128);
  unsigned* h1 = (unsigned*)(arena + 4096);
  unsigned* h2 = pathA ? (unsigned*)(arena + 65536) : (unsigned*)(arena + 20480);
  unsigned* h3 = (unsigned*)(arena + 36864);
  const size_t zlo = 4096;
  const size_t zbytes = (pathA ? needA : needB) - zlo;

  if (!dual) k1 = k0;

  hipMemsetAsync(arena + zlo, 0, zbytes, stream);
  init_ctrl_k<<<1, 64, 0, stream>>>(c0, k0, (dual ? c1 : c0), k1);

  const int nchain = dual ? 2 : 1;
  for (int chain = 0; chain < nchain; ++chain) {
    Ctrl* cc = chain ? c1 : c0;
    if (chain) hipMemsetAsync(arena + zlo, 0, zbytes, stream);
    if (pathA) {
      hist_stage_k<<<HB, HT, 0, stream>>>(x4, n4, xbits, N, h1, cc, 19, 12);
      scan_stage_k<<<1, 1024, 0, stream>>>(h1, 12, cc);
      hist_stage_k<<<HB, HT, 0, stream>>>(x4, n4, xbits, N, h2, cc, 0, 19);
      scan_big1_k<<<512, 256, 0, stream>>>(h2, chunkSums);
      scan_big2_k<<<1, 1024, 0, stream>>>(h2, chunkSums, cc);
    } else {
      hist_stage_k<<<HB, HT, 0, stream>>>(x4, n4, xbits, N, h1, cc, 19, 12);
      scan_stage_k<<<1, 1024, 0, stream>>>(h1, 12, cc);
      hist_stage_k<<<HB, HT, 0, stream>>>(x4, n4, xbits, N, h2, cc, 7, 12);
      scan_stage_k<<<1, 1024, 0, stream>>>(h2, 12, cc);
      hist_stage_k<<<HB, HT, 0, stream>>>(x4, n4, xbits, N, h3, cc, 0, 7);
      scan_stage_k<<<1, 1024, 0, stream>>>(h3, 7, cc);
    }
  }
  combine_thr_k<<<1, 64, 0, stream>>>(c0, (dual ? c1 : c0), lw, hw);
  mask_k<<<HB, HT, 0, stream>>>((const float4*)x, (float4*)d_out, n4,
                                x, (float*)d_out, N, c0);
}